// Round 6
// baseline (888.542 us; speedup 1.0000x reference)
//
#include <hip/hip_runtime.h>
#include <math.h>

#define LATENT 256
#define EMBD 128
#define VOCAB 600
#define NLEV 12
#define NNODES 65536
#define NTREES 32
#define MAXM 6400            // >= count(+13 sigma); multiple of 128
#define INV_N (1.0f/65536.0f)

typedef unsigned short ushort_t;
typedef __attribute__((ext_vector_type(8))) short short8;
typedef __attribute__((ext_vector_type(4))) float float4v;
typedef __attribute__((ext_vector_type(8))) unsigned short u16x8;
typedef __attribute__((ext_vector_type(4))) unsigned short u16x4;

#define GLOBAL_AS __attribute__((address_space(1)))
#define LDS_AS __attribute__((address_space(3)))

__device__ __forceinline__ float sigm(float x){ return 1.0f/(1.0f+expf(-x)); }
__device__ __forceinline__ float bcef(float x, float y){
  return fmaxf(x,0.0f) - x*y + log1pf(expf(-fabsf(x)));
}
__device__ __forceinline__ ushort_t f2bf(float f){
  union{float f; unsigned u;} v; v.f=f;
  unsigned r = v.u + 0x7fffu + ((v.u>>16)&1u);
  return (ushort_t)(r>>16);
}
__device__ __forceinline__ float bf2f(ushort_t u){
  union{unsigned u; float f;} v; v.u = ((unsigned)u)<<16; return v.f;
}

__device__ __forceinline__ void gload_lds(const void* src, void* dst){
  __builtin_amdgcn_global_load_lds((const GLOBAL_AS void*)src, (LDS_AS void*)dst, 16, 0, 0);
}

__device__ __forceinline__ void acc_zero4(float4v acc[4][4]){
  #pragma unroll
  for (int i=0;i<4;i++){
    #pragma unroll
    for (int j=0;j<4;j++){ acc[i][j] = (float4v){0.f,0.f,0.f,0.f}; }
  }
}
__device__ __forceinline__ void acc_zero8(float4v acc[4][8]){
  #pragma unroll
  for (int i=0;i<4;i++){
    #pragma unroll
    for (int j=0;j<8;j++){ acc[i][j] = (float4v){0.f,0.f,0.f,0.f}; }
  }
}

// ---- shared GEMM pieces (m97 structure, T2 swizzle) ----
__device__ __forceinline__ void stageB128(const char* Wb, int strideB, int n0, int k0,
    int srow, int skb, char* BsB, int t){
  #pragma unroll
  for (int i=0;i<4;i++){
    int row = srow + 32*i;
    int kbs = skb ^ ((row&7)<<4);
    const char* src = Wb + (size_t)(n0+row)*strideB + k0*2 + kbs;
    gload_lds(src, BsB + i*4096 + t*16);
  }
}
__device__ __forceinline__ void stageB256(const char* Wb, int strideB, int n0, int k0,
    int srow, int skb, char* BsB, int t){
  #pragma unroll
  for (int i=0;i<8;i++){
    int row = srow + 32*i;
    int kbs = skb ^ ((row&7)<<4);
    const char* src = Wb + (size_t)(n0+row)*strideB + k0*2 + kbs;
    gload_lds(src, BsB + i*4096 + t*16);
  }
}
// direct (compact, padded) A staging: row stride = strideA bytes
__device__ __forceinline__ void stageA128(const char* Ab, int strideA, int m0, int k0,
    int srow, int skb, char* AsB, int t){
  #pragma unroll
  for (int i=0;i<4;i++){
    int row = srow + 32*i;
    int kbs = skb ^ ((row&7)<<4);
    const char* src = Ab + (size_t)(m0+row)*strideA + k0*2 + kbs;
    gload_lds(src, AsB + i*4096 + t*16);
  }
}

__device__ __forceinline__ void mfma_phase4(const char* AsB, const char* BsB,
    float4v acc[4][4], int lane, int wr, int wc){
  #pragma unroll
  for (int kk=0;kk<2;kk++){
    short8 af[4], bfr[4];
    const int kb = kk*64 + (lane>>4)*16;
    #pragma unroll
    for (int mf=0;mf<4;mf++){
      int row = wr*64 + mf*16 + (lane&15);
      af[mf] = *(const short8*)(AsB + row*128 + (kb ^ ((row&7)<<4)));
    }
    #pragma unroll
    for (int nf=0;nf<4;nf++){
      int row = wc*64 + nf*16 + (lane&15);
      bfr[nf] = *(const short8*)(BsB + row*128 + (kb ^ ((row&7)<<4)));
    }
    #pragma unroll
    for (int mf=0;mf<4;mf++){
      #pragma unroll
      for (int nf=0;nf<4;nf++){
        acc[mf][nf] = __builtin_amdgcn_mfma_f32_16x16x32_bf16(af[mf], bfr[nf], acc[mf][nf], 0,0,0);
      }
    }
  }
}
// 4 waves as 2(m)x2(n); wave tile 64 rows x 128 cols
__device__ __forceinline__ void mfma_phase8(const char* AsB, const char* BsB,
    float4v acc[4][8], int lane, int wr2, int wc2){
  #pragma unroll
  for (int kk=0;kk<2;kk++){
    short8 af[4], bfr[8];
    const int kb = kk*64 + (lane>>4)*16;
    #pragma unroll
    for (int mf=0;mf<4;mf++){
      int row = wr2*64 + mf*16 + (lane&15);
      af[mf] = *(const short8*)(AsB + row*128 + (kb ^ ((row&7)<<4)));
    }
    #pragma unroll
    for (int nf=0;nf<8;nf++){
      int row = wc2*128 + nf*16 + (lane&15);
      bfr[nf] = *(const short8*)(BsB + row*128 + (kb ^ ((row&7)<<4)));
    }
    #pragma unroll
    for (int mf=0;mf<4;mf++){
      #pragma unroll
      for (int nf=0;nf<8;nf++){
        acc[mf][nf] = __builtin_amdgcn_mfma_f32_16x16x32_bf16(af[mf], bfr[nf], acc[mf][nf], 0,0,0);
      }
    }
  }
}

__device__ __forceinline__ void epi_store_bf4(ushort_t* C, int N, int m0, int n0,
    int lane, int wr, int wc, float4v acc[4][4]){
  #pragma unroll
  for (int mf=0;mf<4;mf++){
    int rbase = m0 + wr*64 + mf*16 + (lane>>4)*4;
    #pragma unroll
    for (int nf=0;nf<4;nf++){
      int col = n0 + wc*64 + nf*16 + (lane&15);
      #pragma unroll
      for (int r=0;r<4;r++){
        C[(size_t)(rbase+r)*N + col] = f2bf(acc[mf][nf][r]);
      }
    }
  }
}
__device__ __forceinline__ void epi_store_bf8(ushort_t* C, int N, int m0, int n0,
    int lane, int wr2, int wc2, float4v acc[4][8]){
  #pragma unroll
  for (int mf=0;mf<4;mf++){
    int rbase = m0 + wr2*64 + mf*16 + (lane>>4)*4;
    #pragma unroll
    for (int nf=0;nf<8;nf++){
      int col = n0 + wc2*128 + nf*16 + (lane&15);
      #pragma unroll
      for (int r=0;r<4;r++){
        C[(size_t)(rbase+r)*N + col] = f2bf(acc[mf][nf][r]);
      }
    }
  }
}

// ---- setup kernels ----
__global__ void zero_kernel(float* loss, int* counts, float* zpage){
  int t = threadIdx.x;
  if (t==0) *loss = 0.0f;
  if (t<NLEV) counts[t]=0;
  zpage[t] = 0.0f;          // 1KB zero page
}

// W1t[512][512], W2t[640][256], W3hh_t[1024][256] (gate-interleaved rows),
// W3ih_t[1024][128] (gate-interleaved rows), embbf[640][128] (zero-padded)
__global__ void prep_kernel(const float* __restrict__ W_ph1, const float* __restrict__ W_ph2,
    const float* __restrict__ W_gate, const float* __restrict__ W_topo,
    const float* __restrict__ W_pred, const float* __restrict__ W_ih,
    const float* __restrict__ W_hh, const float* __restrict__ emb_table,
    ushort_t* __restrict__ W1t, ushort_t* __restrict__ W2t,
    ushort_t* __restrict__ W3hh, ushort_t* __restrict__ W3ih,
    ushort_t* __restrict__ embbf)
{
  int idx = blockIdx.x*256 + threadIdx.x;
  if (idx < 512*512){
    int o = idx >> 9, k = idx & 511;
    float v;
    if (o < 256) v = (k<256) ? W_ph1[k*256+o] : W_ph2[(k-256)*256+o];
    else         v = (k<256) ? 0.0f : W_gate[(k-256)*256+(o-256)];
    W1t[idx] = f2bf(v);
    return;
  }
  idx -= 512*512;
  if (idx < 640*256){
    int o = idx >> 8, k = idx & 255;
    float v = 0.0f;
    if (o < 3) v = W_topo[k*3+o];
    else if (o >= 8 && o < 608) v = W_pred[k*VOCAB + (o-8)];
    W2t[idx] = f2bf(v);
    return;
  }
  idx -= 640*256;
  if (idx < 1024*256){
    int r = idx >> 8, k = idx & 255;
    int orig = (r&3)*256 + (r>>2);       // row = 4*latent + gate (i,f,g,o)
    W3hh[idx] = f2bf(W_hh[orig*256+k]);
    return;
  }
  idx -= 1024*256;
  if (idx < 1024*128){
    int r = idx >> 7, k = idx & 127;
    int orig = (r&3)*256 + (r>>2);
    W3ih[idx] = f2bf(W_ih[orig*128+k]);
    return;
  }
  idx -= 1024*128;
  if (idx < 640*128){
    int r = idx >> 7, k = idx & 127;
    embbf[idx] = (r < VOCAB) ? f2bf(emb_table[r*EMBD+k]) : (ushort_t)0;
  }
}

// EG[640][1024] = embbf(640x128) @ W3ih(1024x128)^T  -- once per call
__global__ __launch_bounds__(256) void eg_gemm(
    const ushort_t* __restrict__ embbf, const ushort_t* __restrict__ W3ih,
    ushort_t* __restrict__ EG)
{
  const int m0 = blockIdx.x * 128;
  const int n0 = blockIdx.y * 128;
  __shared__ ushort_t As[128*64];
  __shared__ ushort_t Bs[128*64];
  char* AsB = (char*)As; char* BsB = (char*)Bs;
  const int t = threadIdx.x, lane = t&63, wv = t>>6, wr = wv>>1, wc = wv&1;
  const int srow = t>>3, skb = (t&7)*16;
  float4v acc[4][4];
  acc_zero4(acc);
  for (int k0 = 0; k0 < 128; k0 += 64){
    stageA128((const char*)embbf, 256, m0, k0, srow, skb, AsB, t);
    stageB128((const char*)W3ih, 256, n0, k0, srow, skb, BsB, t);
    __syncthreads();
    mfma_phase4(AsB, BsB, acc, lane, wr, wc);
    __syncthreads();
  }
  epi_store_bf4(EG, 1024, m0, n0, lane, wr, wc, acc);
}

__global__ __launch_bounds__(LATENT) void root_kernel(const float* __restrict__ z,
    const float* __restrict__ W, const float* __restrict__ b, float* __restrict__ root_h){
  __shared__ float zs[LATENT];
  int bi = blockIdx.x; int t = threadIdx.x;
  zs[t] = z[bi*LATENT+t];
  __syncthreads();
  float acc = b[t];
  for (int k=0;k<LATENT;k++) acc += zs[k]*W[t*LATENT+k];
  root_h[bi*LATENT+t] = acc;
}

__global__ __launch_bounds__(LATENT) void init_kernel(const int* __restrict__ node_level,
    const int* __restrict__ tree_id, const float* __restrict__ root_h,
    ushort_t* __restrict__ h_state, ushort_t* __restrict__ c_state){
  int t = threadIdx.x;
  for (int n = blockIdx.x; n < NNODES; n += gridDim.x){
    int lvl = node_level[n];
    ushort_t h = 0;
    if (lvl==0) h = f2bf(root_h[tree_id[n]*LATENT + t]);
    h_state[(size_t)n*LATENT+t]=h;
    c_state[(size_t)n*LATENT+t]=0;
  }
}

// LDS-histogram list builder: 1 global atomic per (block, level)
__global__ __launch_bounds__(256) void build_lists_kernel(const int* __restrict__ node_level,
    int* __restrict__ counts, int* __restrict__ lists){
  __shared__ int lcnt[NLEV];
  __shared__ int lbase[NLEV];
  int tt = threadIdx.x;
  int n = blockIdx.x*256 + tt;
  if (tt < NLEV) lcnt[tt] = 0;
  __syncthreads();
  int lvl = node_level[n];
  int pos = atomicAdd(&lcnt[lvl], 1);
  __syncthreads();
  if (tt < NLEV) lbase[tt] = atomicAdd(&counts[tt], lcnt[tt]);
  __syncthreads();
  if (lvl >= 1){
    int p = lbase[lvl] + pos;
    if (p < MAXM) lists[lvl*MAXM + p] = n;
  }
}

// ---- K1: gemm1, indirect A ([h_par|h_sib], K=512), BN=256 (nt=0: pred, nt=1: gate) ----
__global__ __launch_bounds__(256) void k1_gemm(
    const int* __restrict__ counts, int lvl, const int* __restrict__ lists,
    const int* __restrict__ parent_idx, const int* __restrict__ sibling_idx,
    const int* __restrict__ has_prev, const ushort_t* __restrict__ h_state,
    const char* __restrict__ zpage, const ushort_t* __restrict__ W1t,
    ushort_t* __restrict__ C1)
{
  const int count = min(counts[lvl], MAXM);
  const int m0 = blockIdx.x * 128;
  if (m0 >= count) return;
  const int nt = blockIdx.y;
  const int n0 = nt * 256;
  __shared__ ushort_t As[128*64];
  __shared__ ushort_t Bs[256*64];
  char* AsB = (char*)As; char* BsB = (char*)Bs;
  const int t = threadIdx.x, lane = t&63, wv = t>>6, wr2 = wv>>1, wc2 = wv&1;
  const int srow = t>>3, skb = (t&7)*16;

  const char* pb[4]; const char* sb[4]; int kbs[4];
  #pragma unroll
  for (int i=0;i<4;i++){
    int row = srow + 32*i;
    kbs[i] = skb ^ ((row&7)<<4);
    int m = m0 + row;
    if (m < count){
      int node = lists[lvl*MAXM + m];
      pb[i] = (const char*)(h_state + (size_t)parent_idx[node]*LATENT);
      sb[i] = (has_prev[node] > 0) ? (const char*)(h_state + (size_t)sibling_idx[node]*LATENT)
                                   : zpage;
    } else { pb[i] = zpage; sb[i] = zpage; }
  }

  float4v acc[4][8];
  acc_zero8(acc);

  // gate rows (o>=256) have zero weights for k<256
  const int kstart = nt ? 256 : 0;
  for (int k0 = kstart; k0 < 512; k0 += 64){
    #pragma unroll
    for (int i=0;i<4;i++){
      const char* src = (k0 < 256) ? pb[i] + (k0*2 + kbs[i])
                                   : sb[i] + ((k0-256)*2 + kbs[i]);
      gload_lds(src, AsB + i*4096 + t*16);
    }
    stageB256((const char*)W1t, 1024, n0, k0, srow, skb, BsB, t);
    __syncthreads();
    mfma_phase8(AsB, BsB, acc, lane, wr2, wc2);
    __syncthreads();
  }
  epi_store_bf8(C1, 512, m0, n0, lane, wr2, wc2, acc);
}

// ---- mid: A2 = tanh(pred_pre+b), PU = hp + sigm(gate_pre+b)*hs, Cpar gather ----
__global__ __launch_bounds__(256) void mid_kernel(
    const int* __restrict__ counts, int lvl, const int* __restrict__ lists,
    const int* __restrict__ parent_idx, const int* __restrict__ sibling_idx,
    const int* __restrict__ has_prev, const ushort_t* __restrict__ h_state,
    const ushort_t* __restrict__ c_state, const ushort_t* __restrict__ C1,
    const float* __restrict__ b_ph1, const float* __restrict__ b_ph2,
    const float* __restrict__ b_gate,
    ushort_t* __restrict__ A2, ushort_t* __restrict__ PU, ushort_t* __restrict__ Cpar)
{
  const int count = min(counts[lvl], MAXM);
  const int Mt = (count+127)&~127;
  const int t = threadIdx.x;
  const float bp = b_ph1[t] + b_ph2[t];
  const float bg = b_gate[t];
  for (int m = blockIdx.x; m < Mt; m += gridDim.x){
    if (m < count){
      int node = lists[lvl*MAXM + m];
      int pi = parent_idx[node];
      float hp = bf2f(h_state[(size_t)pi*LATENT + t]);
      float hs = (has_prev[node] > 0) ? bf2f(h_state[(size_t)sibling_idx[node]*LATENT + t]) : 0.0f;
      float pre  = bf2f(C1[(size_t)m*512 + t]) + bp;
      float gpre = bf2f(C1[(size_t)m*512 + 256 + t]) + bg;
      A2[(size_t)m*LATENT + t] = f2bf(tanhf(pre));
      PU[(size_t)m*LATENT + t] = f2bf(hp + sigm(gpre)*hs);
      Cpar[(size_t)m*LATENT + t] = c_state[(size_t)pi*LATENT + t];
    } else {
      A2[(size_t)m*LATENT + t] = 0;
      PU[(size_t)m*LATENT + t] = 0;
    }
  }
}

// ---- K2: gemm2 (A2 x W2t -> C2, BN=128) + gemm3 (PU x W3hh -> C3, BN=256) ----
__global__ __launch_bounds__(256) void k2_fused(
    const int* __restrict__ counts, int lvl,
    const ushort_t* __restrict__ A2, const ushort_t* __restrict__ PU,
    const ushort_t* __restrict__ W2t, const ushort_t* __restrict__ W3hh,
    ushort_t* __restrict__ C2, ushort_t* __restrict__ C3)
{
  const int count = min(counts[lvl], MAXM);
  const int id = blockIdx.x;
  __shared__ ushort_t As[128*64];
  __shared__ ushort_t Bs[256*64];
  char* AsB = (char*)As; char* BsB = (char*)Bs;
  const int t = threadIdx.x, lane = t&63, wv = t>>6;
  const int srow = t>>3, skb = (t&7)*16;

  if (id < 250){
    // gemm2: M x 640, K=256, BN=128
    const int m0 = (id/5)*128; if (m0 >= count) return;
    const int n0 = (id%5)*128;
    const int wr = wv>>1, wc = wv&1;
    float4v acc[4][4];
    acc_zero4(acc);
    for (int k0 = 0; k0 < 256; k0 += 64){
      stageA128((const char*)A2, 512, m0, k0, srow, skb, AsB, t);
      stageB128((const char*)W2t, 512, n0, k0, srow, skb, BsB, t);
      __syncthreads();
      mfma_phase4(AsB, BsB, acc, lane, wr, wc);
      __syncthreads();
    }
    epi_store_bf4(C2, 640, m0, n0, lane, wr, wc, acc);
  } else {
    // gemm3: M x 1024, K=256, BN=256, A = PU (compact, zero-padded)
    const int id2 = id - 250;
    const int m0 = (id2>>2)*128; if (m0 >= count) return;
    const int n0 = (id2&3)*256;
    const int wr2 = wv>>1, wc2 = wv&1;
    float4v acc[4][8];
    acc_zero8(acc);
    for (int k0 = 0; k0 < 256; k0 += 64){
      stageA128((const char*)PU, 512, m0, k0, srow, skb, AsB, t);
      stageB256((const char*)W3hh, 512, n0, k0, srow, skb, BsB, t);
      __syncthreads();
      mfma_phase8(AsB, BsB, acc, lane, wr2, wc2);
      __syncthreads();
    }
    epi_store_bf8(C3, 1024, m0, n0, lane, wr2, wc2, acc);
  }
}

// ---- K3: loss (blocks 0..511) + LSTM finish & scatter (blocks 512..1023) ----
__global__ __launch_bounds__(256) void k3_losslstm(
    const int* __restrict__ counts, int lvl, const int* __restrict__ lists,
    const ushort_t* __restrict__ C2, const ushort_t* __restrict__ C3,
    const ushort_t* __restrict__ Cpar, const ushort_t* __restrict__ EG,
    const float* __restrict__ b_topo, const float* __restrict__ b_pred,
    const float* __restrict__ b_ih, const float* __restrict__ b_hh,
    const int* __restrict__ features, const int* __restrict__ is_parent,
    const int* __restrict__ has_sib, const int* __restrict__ is_res,
    float* __restrict__ loss,
    ushort_t* __restrict__ h_state, ushort_t* __restrict__ c_state)
{
  const int count = min(counts[lvl], MAXM);
  if (blockIdx.x < 512){
    __shared__ float lsum[4];
    const int lane = threadIdx.x & 63;
    const int wvi = threadIdx.x >> 6;
    if (threadIdx.x < 4) lsum[threadIdx.x] = 0.0f;
    __syncthreads();
    for (int m = blockIdx.x*4 + wvi; m < count; m += 2048){
      const ushort_t* row = C2 + (size_t)m*640;
      int node = lists[lvl*MAXM + m];
      int feat = features[node];
      float mx = -1e30f, lf = 0.0f;
      float vals[16];
      #pragma unroll
      for (int i=0;i<2;i++){
        int s = lane + 64*i;
        if (s < 75){
          u16x8 raw = *(const u16x8*)((const char*)row + 16 + 16*s);
          float4v bp0 = *(const float4v*)(b_pred + 8*s);
          float4v bp1 = *(const float4v*)(b_pred + 8*s + 4);
          #pragma unroll
          for (int j=0;j<8;j++){
            float b = (j<4) ? bp0[j] : bp1[j-4];
            float v = bf2f(raw[j]) + b;
            vals[8*i+j] = v;
            mx = fmaxf(mx, v);
            if (8*s + j == feat) lf = v;
          }
        } else {
          #pragma unroll
          for (int j=0;j<8;j++) vals[8*i+j] = -1e30f;
        }
      }
      #pragma unroll
      for (int off=32;off>=1;off>>=1) mx = fmaxf(mx, __shfl_xor(mx, off));
      float s = 0.0f;
      #pragma unroll
      for (int i=0;i<16;i++) s += expf(vals[i]-mx);
      #pragma unroll
      for (int off=32;off>=1;off>>=1) s += __shfl_xor(s, off);
      #pragma unroll
      for (int off=32;off>=1;off>>=1) lf += __shfl_xor(lf, off);
      if (lane == 0){
        float ce = logf(s) + mx - lf;
        float bce = bcef(bf2f(row[0])+b_topo[0], (float)is_parent[node])
                  + bcef(bf2f(row[1])+b_topo[1], (float)has_sib[node])
                  + bcef(bf2f(row[2])+b_topo[2], (float)is_res[node]);
        atomicAdd(&lsum[wvi], ce + bce);
      }
    }
    __syncthreads();
    if (threadIdx.x == 0){
      atomicAdd(loss, (lsum[0]+lsum[1]+lsum[2]+lsum[3]) * INV_N);
    }
  } else {
    const int t = threadIdx.x;
    const float bi = b_ih[t]       + b_hh[t];
    const float bf = b_ih[256+t]   + b_hh[256+t];
    const float bg = b_ih[512+t]   + b_hh[512+t];
    const float bo = b_ih[768+t]   + b_hh[768+t];
    for (int m = (int)blockIdx.x - 512; m < count; m += 512){
      int node = lists[lvl*MAXM + m];
      int feat = features[node];
      u16x4 gv = *(const u16x4*)(C3 + (size_t)m*1024 + 4*t);     // PU@W_hh, interleaved
      u16x4 ev = *(const u16x4*)(EG + (size_t)feat*1024 + 4*t);  // emb@W_ih, interleaved
      float i_ = sigm(bf2f(gv[0]) + bf2f(ev[0]) + bi);
      float f_ = sigm(bf2f(gv[1]) + bf2f(ev[1]) + bf);
      float gg = tanhf(bf2f(gv[2]) + bf2f(ev[2]) + bg);
      float o_ = sigm(bf2f(gv[3]) + bf2f(ev[3]) + bo);
      float cn = f_*bf2f(Cpar[(size_t)m*LATENT+t]) + i_*gg;
      float hn = o_*tanhf(cn);
      h_state[(size_t)node*LATENT+t] = f2bf(hn);
      c_state[(size_t)node*LATENT+t] = f2bf(cn);
    }
  }
}

extern "C" void kernel_launch(void* const* d_in, const int* in_sizes, int n_in,
                              void* d_out, int out_size, void* d_ws, size_t ws_size,
                              hipStream_t stream)
{
  const float* z         = (const float*)d_in[0];
  const float* emb_table = (const float*)d_in[1];
  const float* W_l2h     = (const float*)d_in[2];
  const float* b_l2h     = (const float*)d_in[3];
  const float* W_ih      = (const float*)d_in[4];
  const float* W_hh      = (const float*)d_in[5];
  const float* b_ih      = (const float*)d_in[6];
  const float* b_hh      = (const float*)d_in[7];
  const float* W_ph1     = (const float*)d_in[8];
  const float* b_ph1     = (const float*)d_in[9];
  const float* W_ph2     = (const float*)d_in[10];
  const float* b_ph2     = (const float*)d_in[11];
  const float* W_gate    = (const float*)d_in[12];
  const float* b_gate    = (const float*)d_in[13];
  const float* W_topo    = (const float*)d_in[14];
  const float* b_topo    = (const float*)d_in[15];
  const float* W_pred    = (const float*)d_in[16];
  const float* b_pred    = (const float*)d_in[17];
  const int* features    = (const int*)d_in[18];
  const int* node_level  = (const int*)d_in[19];
  const int* parent_idx  = (const int*)d_in[20];
  const int* sibling_idx = (const int*)d_in[21];
  const int* has_prev    = (const int*)d_in[22];
  const int* tree_id     = (const int*)d_in[23];
  const int* is_parent   = (const int*)d_in[24];
  const int* has_sib     = (const int*)d_in[25];
  const int* is_res      = (const int*)d_in[26];

  char* ws = (char*)d_ws;
  size_t off = 0;
  auto alloc = [&](size_t bytes)->char*{
    char* p = ws + off; off += (bytes + 255) & ~(size_t)255; return p;
  };
  ushort_t* h_state = (ushort_t*)alloc((size_t)NNODES*LATENT*2);   // 33.5 MB
  ushort_t* c_state = (ushort_t*)alloc((size_t)NNODES*LATENT*2);   // 33.5 MB
  ushort_t* A2      = (ushort_t*)alloc((size_t)MAXM*LATENT*2);
  ushort_t* PU      = (ushort_t*)alloc((size_t)MAXM*LATENT*2);
  ushort_t* C1      = (ushort_t*)alloc((size_t)MAXM*512*2);
  ushort_t* C2      = (ushort_t*)alloc((size_t)MAXM*640*2);
  ushort_t* C3      = (ushort_t*)alloc((size_t)MAXM*1024*2);
  ushort_t* Cpar    = (ushort_t*)alloc((size_t)MAXM*LATENT*2);
  ushort_t* W1t     = (ushort_t*)alloc((size_t)512*512*2);
  ushort_t* W2t     = (ushort_t*)alloc((size_t)640*256*2);
  ushort_t* W3hh    = (ushort_t*)alloc((size_t)1024*256*2);
  ushort_t* W3ih    = (ushort_t*)alloc((size_t)1024*128*2);
  ushort_t* embbf   = (ushort_t*)alloc((size_t)640*128*2);
  ushort_t* EG      = (ushort_t*)alloc((size_t)640*1024*2);
  float*    root_h  = (float*)alloc((size_t)NTREES*LATENT*4);
  int*      lists   = (int*)alloc((size_t)NLEV*MAXM*4);
  int*      counts  = (int*)alloc(64);
  float*    zpage   = (float*)alloc(1024);
  float*    loss    = (float*)d_out;

  zero_kernel<<<1,256,0,stream>>>(loss, counts, zpage);
  prep_kernel<<<3520,256,0,stream>>>(W_ph1,W_ph2,W_gate,W_topo,W_pred,W_ih,W_hh,emb_table,
                                     W1t,W2t,W3hh,W3ih,embbf);
  eg_gemm<<<dim3(5,8),256,0,stream>>>(embbf, W3ih, EG);
  root_kernel<<<NTREES,LATENT,0,stream>>>(z, W_l2h, b_l2h, root_h);
  init_kernel<<<2048,LATENT,0,stream>>>(node_level, tree_id, root_h, h_state, c_state);
  build_lists_kernel<<<NNODES/256,256,0,stream>>>(node_level, counts, lists);

  for (int lvl=1; lvl<NLEV; lvl++){
    k1_gemm<<<dim3(MAXM/128,2),256,0,stream>>>(counts, lvl, lists,
        parent_idx, sibling_idx, has_prev, h_state, (const char*)zpage, W1t, C1);
    mid_kernel<<<512,256,0,stream>>>(counts, lvl, lists, parent_idx, sibling_idx,
        has_prev, h_state, c_state, C1, b_ph1, b_ph2, b_gate, A2, PU, Cpar);
    k2_fused<<<450,256,0,stream>>>(counts, lvl, A2, PU, W2t, W3hh, C2, C3);
    k3_losslstm<<<1024,256,0,stream>>>(counts, lvl, lists, C2, C3, Cpar, EG,
        b_topo, b_pred, b_ih, b_hh, features, is_parent, has_sib, is_res,
        loss, h_state, c_state);
  }
}

// Round 7
// 795.927 us; speedup vs baseline: 1.1164x; 1.1164x over previous
//
#include <hip/hip_runtime.h>
#include <math.h>

#define LATENT 256
#define EMBD 128
#define VOCAB 600
#define NLEV 12
#define NNODES 65536
#define NTREES 32
#define MAXM 6400            // >= count(+13 sigma); multiple of 128
#define INV_N (1.0f/65536.0f)

typedef unsigned short ushort_t;
typedef __attribute__((ext_vector_type(8))) short short8;
typedef __attribute__((ext_vector_type(4))) float float4v;
typedef __attribute__((ext_vector_type(8))) unsigned short u16x8;
typedef __attribute__((ext_vector_type(4))) unsigned short u16x4;

#define GLOBAL_AS __attribute__((address_space(1)))
#define LDS_AS __attribute__((address_space(3)))

__device__ __forceinline__ float sigm(float x){ return 1.0f/(1.0f+expf(-x)); }
__device__ __forceinline__ float bcef(float x, float y){
  return fmaxf(x,0.0f) - x*y + log1pf(expf(-fabsf(x)));
}
__device__ __forceinline__ ushort_t f2bf(float f){
  union{float f; unsigned u;} v; v.f=f;
  unsigned r = v.u + 0x7fffu + ((v.u>>16)&1u);
  return (ushort_t)(r>>16);
}
__device__ __forceinline__ float bf2f(ushort_t u){
  union{unsigned u; float f;} v; v.u = ((unsigned)u)<<16; return v.f;
}

__device__ __forceinline__ void gload_lds(const void* src, void* dst){
  __builtin_amdgcn_global_load_lds((const GLOBAL_AS void*)src, (LDS_AS void*)dst, 16, 0, 0);
}

__device__ __forceinline__ void acc_zero4(float4v acc[4][4]){
  #pragma unroll
  for (int i=0;i<4;i++){
    #pragma unroll
    for (int j=0;j<4;j++){ acc[i][j] = (float4v){0.f,0.f,0.f,0.f}; }
  }
}

// ---- shared GEMM pieces (m97 structure, T2 swizzle) ----
__device__ __forceinline__ void stageB128(const char* Wb, int strideB, int n0, int k0,
    int srow, int skb, char* BsB, int t){
  #pragma unroll
  for (int i=0;i<4;i++){
    int row = srow + 32*i;
    int kbs = skb ^ ((row&7)<<4);
    const char* src = Wb + (size_t)(n0+row)*strideB + k0*2 + kbs;
    gload_lds(src, BsB + i*4096 + t*16);
  }
}
// direct (compact, padded) A staging: row stride = strideA bytes
__device__ __forceinline__ void stageA128(const char* Ab, int strideA, int m0, int k0,
    int srow, int skb, char* AsB, int t){
  #pragma unroll
  for (int i=0;i<4;i++){
    int row = srow + 32*i;
    int kbs = skb ^ ((row&7)<<4);
    const char* src = Ab + (size_t)(m0+row)*strideA + k0*2 + kbs;
    gload_lds(src, AsB + i*4096 + t*16);
  }
}

__device__ __forceinline__ void mfma_phase4(const char* AsB, const char* BsB,
    float4v acc[4][4], int lane, int wr, int wc){
  #pragma unroll
  for (int kk=0;kk<2;kk++){
    short8 af[4], bfr[4];
    const int kb = kk*64 + (lane>>4)*16;
    #pragma unroll
    for (int mf=0;mf<4;mf++){
      int row = wr*64 + mf*16 + (lane&15);
      af[mf] = *(const short8*)(AsB + row*128 + (kb ^ ((row&7)<<4)));
    }
    #pragma unroll
    for (int nf=0;nf<4;nf++){
      int row = wc*64 + nf*16 + (lane&15);
      bfr[nf] = *(const short8*)(BsB + row*128 + (kb ^ ((row&7)<<4)));
    }
    #pragma unroll
    for (int mf=0;mf<4;mf++){
      #pragma unroll
      for (int nf=0;nf<4;nf++){
        acc[mf][nf] = __builtin_amdgcn_mfma_f32_16x16x32_bf16(af[mf], bfr[nf], acc[mf][nf], 0,0,0);
      }
    }
  }
}

__device__ __forceinline__ void epi_store_bf4(ushort_t* C, int N, int m0, int n0,
    int lane, int wr, int wc, float4v acc[4][4]){
  #pragma unroll
  for (int mf=0;mf<4;mf++){
    int rbase = m0 + wr*64 + mf*16 + (lane>>4)*4;
    #pragma unroll
    for (int nf=0;nf<4;nf++){
      int col = n0 + wc*64 + nf*16 + (lane&15);
      #pragma unroll
      for (int r=0;r<4;r++){
        C[(size_t)(rbase+r)*N + col] = f2bf(acc[mf][nf][r]);
      }
    }
  }
}

// ---- setup kernels ----
__global__ void zero_kernel(float* loss, int* counts, float* zpage){
  int t = threadIdx.x;
  if (t==0) *loss = 0.0f;
  if (t<NLEV) counts[t]=0;
  zpage[t] = 0.0f;          // 1KB zero page
}

// W1t[512][512], W2t[640][256], W3hh_t[1024][256] (gate-interleaved rows),
// W3ih_t[1024][128] (gate-interleaved rows), embbf[640][128] (zero-padded)
__global__ void prep_kernel(const float* __restrict__ W_ph1, const float* __restrict__ W_ph2,
    const float* __restrict__ W_gate, const float* __restrict__ W_topo,
    const float* __restrict__ W_pred, const float* __restrict__ W_ih,
    const float* __restrict__ W_hh, const float* __restrict__ emb_table,
    ushort_t* __restrict__ W1t, ushort_t* __restrict__ W2t,
    ushort_t* __restrict__ W3hh, ushort_t* __restrict__ W3ih,
    ushort_t* __restrict__ embbf)
{
  int idx = blockIdx.x*256 + threadIdx.x;
  if (idx < 512*512){
    int o = idx >> 9, k = idx & 511;
    float v;
    if (o < 256) v = (k<256) ? W_ph1[k*256+o] : W_ph2[(k-256)*256+o];
    else         v = (k<256) ? 0.0f : W_gate[(k-256)*256+(o-256)];
    W1t[idx] = f2bf(v);
    return;
  }
  idx -= 512*512;
  if (idx < 640*256){
    int o = idx >> 8, k = idx & 255;
    float v = 0.0f;
    if (o < 3) v = W_topo[k*3+o];
    else if (o >= 8 && o < 608) v = W_pred[k*VOCAB + (o-8)];
    W2t[idx] = f2bf(v);
    return;
  }
  idx -= 640*256;
  if (idx < 1024*256){
    int r = idx >> 8, k = idx & 255;
    int orig = (r&3)*256 + (r>>2);       // row = 4*latent + gate (i,f,g,o)
    W3hh[idx] = f2bf(W_hh[orig*256+k]);
    return;
  }
  idx -= 1024*256;
  if (idx < 1024*128){
    int r = idx >> 7, k = idx & 127;
    int orig = (r&3)*256 + (r>>2);
    W3ih[idx] = f2bf(W_ih[orig*128+k]);
    return;
  }
  idx -= 1024*128;
  if (idx < 640*128){
    int r = idx >> 7, k = idx & 127;
    embbf[idx] = (r < VOCAB) ? f2bf(emb_table[r*EMBD+k]) : (ushort_t)0;
  }
}

// EG[640][1024] = embbf(640x128) @ W3ih(1024x128)^T  -- once per call
__global__ __launch_bounds__(256) void eg_gemm(
    const ushort_t* __restrict__ embbf, const ushort_t* __restrict__ W3ih,
    ushort_t* __restrict__ EG)
{
  const int m0 = blockIdx.x * 128;
  const int n0 = blockIdx.y * 128;
  __shared__ ushort_t As[128*64];
  __shared__ ushort_t Bs[128*64];
  char* AsB = (char*)As; char* BsB = (char*)Bs;
  const int t = threadIdx.x, lane = t&63, wv = t>>6, wr = wv>>1, wc = wv&1;
  const int srow = t>>3, skb = (t&7)*16;
  float4v acc[4][4];
  acc_zero4(acc);
  for (int k0 = 0; k0 < 128; k0 += 64){
    stageA128((const char*)embbf, 256, m0, k0, srow, skb, AsB, t);
    stageB128((const char*)W3ih, 256, n0, k0, srow, skb, BsB, t);
    __syncthreads();
    mfma_phase4(AsB, BsB, acc, lane, wr, wc);
    __syncthreads();
  }
  epi_store_bf4(EG, 1024, m0, n0, lane, wr, wc, acc);
}

__global__ __launch_bounds__(LATENT) void root_kernel(const float* __restrict__ z,
    const float* __restrict__ W, const float* __restrict__ b, float* __restrict__ root_h){
  __shared__ float zs[LATENT];
  int bi = blockIdx.x; int t = threadIdx.x;
  zs[t] = z[bi*LATENT+t];
  __syncthreads();
  float acc = b[t];
  for (int k=0;k<LATENT;k++) acc += zs[k]*W[t*LATENT+k];
  root_h[bi*LATENT+t] = acc;
}

__global__ __launch_bounds__(LATENT) void init_kernel(const int* __restrict__ node_level,
    const int* __restrict__ tree_id, const float* __restrict__ root_h,
    ushort_t* __restrict__ h_state, ushort_t* __restrict__ c_state){
  int t = threadIdx.x;
  for (int n = blockIdx.x; n < NNODES; n += gridDim.x){
    int lvl = node_level[n];
    ushort_t h = 0;
    if (lvl==0) h = f2bf(root_h[tree_id[n]*LATENT + t]);
    h_state[(size_t)n*LATENT+t]=h;
    c_state[(size_t)n*LATENT+t]=0;
  }
}

// LDS-histogram list builder: 1 global atomic per (block, level)
__global__ __launch_bounds__(256) void build_lists_kernel(const int* __restrict__ node_level,
    int* __restrict__ counts, int* __restrict__ lists){
  __shared__ int lcnt[NLEV];
  __shared__ int lbase[NLEV];
  int tt = threadIdx.x;
  int n = blockIdx.x*256 + tt;
  if (tt < NLEV) lcnt[tt] = 0;
  __syncthreads();
  int lvl = node_level[n];
  int pos = atomicAdd(&lcnt[lvl], 1);
  __syncthreads();
  if (tt < NLEV) lbase[tt] = atomicAdd(&counts[tt], lcnt[tt]);
  __syncthreads();
  if (lvl >= 1){
    int p = lbase[lvl] + pos;
    if (p < MAXM) lists[lvl*MAXM + p] = n;
  }
}

// ---- K1: gemm1, indirect A ([h_par|h_sib], K=512), BN=128; gate tiles skip K<256 ----
__global__ __launch_bounds__(256) void k1_gemm(
    const int* __restrict__ counts, int lvl, const int* __restrict__ lists,
    const int* __restrict__ parent_idx, const int* __restrict__ sibling_idx,
    const int* __restrict__ has_prev, const ushort_t* __restrict__ h_state,
    const char* __restrict__ zpage, const ushort_t* __restrict__ W1t,
    ushort_t* __restrict__ C1)
{
  const int count = min(counts[lvl], MAXM);
  const int m0 = blockIdx.x * 128;
  if (m0 >= count) return;
  const int n0 = blockIdx.y * 128;
  __shared__ ushort_t As[128*64];
  __shared__ ushort_t Bs[128*64];
  char* AsB = (char*)As; char* BsB = (char*)Bs;
  const int t = threadIdx.x, lane = t&63, wv = t>>6, wr = wv>>1, wc = wv&1;
  const int srow = t>>3, skb = (t&7)*16;

  const char* pb[4]; const char* sb[4]; int kbs[4];
  #pragma unroll
  for (int i=0;i<4;i++){
    int row = srow + 32*i;
    kbs[i] = skb ^ ((row&7)<<4);
    int m = m0 + row;
    if (m < count){
      int node = lists[lvl*MAXM + m];
      pb[i] = (const char*)(h_state + (size_t)parent_idx[node]*LATENT);
      sb[i] = (has_prev[node] > 0) ? (const char*)(h_state + (size_t)sibling_idx[node]*LATENT)
                                   : zpage;
    } else { pb[i] = zpage; sb[i] = zpage; }
  }

  float4v acc[4][4];
  acc_zero4(acc);

  // gate rows (o>=256) have zero weights for k<256
  const int kstart = (n0 >= 256) ? 256 : 0;
  for (int k0 = kstart; k0 < 512; k0 += 64){
    #pragma unroll
    for (int i=0;i<4;i++){
      const char* src = (k0 < 256) ? pb[i] + (k0*2 + kbs[i])
                                   : sb[i] + ((k0-256)*2 + kbs[i]);
      gload_lds(src, AsB + i*4096 + t*16);
    }
    stageB128((const char*)W1t, 1024, n0, k0, srow, skb, BsB, t);
    __syncthreads();
    mfma_phase4(AsB, BsB, acc, lane, wr, wc);
    __syncthreads();
  }
  epi_store_bf4(C1, 512, m0, n0, lane, wr, wc, acc);
}

// ---- mid: A2 = tanh(pred_pre+b), PU = hp + sigm(gate_pre+b)*hs, Cpar gather ----
__global__ __launch_bounds__(256) void mid_kernel(
    const int* __restrict__ counts, int lvl, const int* __restrict__ lists,
    const int* __restrict__ parent_idx, const int* __restrict__ sibling_idx,
    const int* __restrict__ has_prev, const ushort_t* __restrict__ h_state,
    const ushort_t* __restrict__ c_state, const ushort_t* __restrict__ C1,
    const float* __restrict__ b_ph1, const float* __restrict__ b_ph2,
    const float* __restrict__ b_gate,
    ushort_t* __restrict__ A2, ushort_t* __restrict__ PU, ushort_t* __restrict__ Cpar)
{
  const int count = min(counts[lvl], MAXM);
  const int Mt = (count+127)&~127;
  const int t = threadIdx.x;
  const float bp = b_ph1[t] + b_ph2[t];
  const float bg = b_gate[t];
  for (int m = blockIdx.x; m < Mt; m += gridDim.x){
    if (m < count){
      int node = lists[lvl*MAXM + m];
      int pi = parent_idx[node];
      float hp = bf2f(h_state[(size_t)pi*LATENT + t]);
      float hs = (has_prev[node] > 0) ? bf2f(h_state[(size_t)sibling_idx[node]*LATENT + t]) : 0.0f;
      float pre  = bf2f(C1[(size_t)m*512 + t]) + bp;
      float gpre = bf2f(C1[(size_t)m*512 + 256 + t]) + bg;
      A2[(size_t)m*LATENT + t] = f2bf(tanhf(pre));
      PU[(size_t)m*LATENT + t] = f2bf(hp + sigm(gpre)*hs);
      Cpar[(size_t)m*LATENT + t] = c_state[(size_t)pi*LATENT + t];
    } else {
      A2[(size_t)m*LATENT + t] = 0;
      PU[(size_t)m*LATENT + t] = 0;
    }
  }
}

// ---- K2: gemm2 (A2 x W2t -> C2) + gemm3 (PU x W3hh -> C3), both BN=128 ----
__global__ __launch_bounds__(256) void k2_fused(
    const int* __restrict__ counts, int lvl,
    const ushort_t* __restrict__ A2, const ushort_t* __restrict__ PU,
    const ushort_t* __restrict__ W2t, const ushort_t* __restrict__ W3hh,
    ushort_t* __restrict__ C2, ushort_t* __restrict__ C3)
{
  const int count = min(counts[lvl], MAXM);
  const int id = blockIdx.x;
  __shared__ ushort_t As[128*64];
  __shared__ ushort_t Bs[128*64];
  char* AsB = (char*)As; char* BsB = (char*)Bs;
  const int t = threadIdx.x, lane = t&63, wv = t>>6, wr = wv>>1, wc = wv&1;
  const int srow = t>>3, skb = (t&7)*16;

  if (id < 250){
    // gemm2: M x 640, K=256
    const int m0 = (id/5)*128; if (m0 >= count) return;
    const int n0 = (id%5)*128;
    float4v acc[4][4];
    acc_zero4(acc);
    for (int k0 = 0; k0 < 256; k0 += 64){
      stageA128((const char*)A2, 512, m0, k0, srow, skb, AsB, t);
      stageB128((const char*)W2t, 512, n0, k0, srow, skb, BsB, t);
      __syncthreads();
      mfma_phase4(AsB, BsB, acc, lane, wr, wc);
      __syncthreads();
    }
    epi_store_bf4(C2, 640, m0, n0, lane, wr, wc, acc);
  } else {
    // gemm3: M x 1024, K=256, A = PU (compact, zero-padded)
    const int id2 = id - 250;
    const int m0 = (id2>>3)*128; if (m0 >= count) return;
    const int n0 = (id2&7)*128;
    float4v acc[4][4];
    acc_zero4(acc);
    for (int k0 = 0; k0 < 256; k0 += 64){
      stageA128((const char*)PU, 512, m0, k0, srow, skb, AsB, t);
      stageB128((const char*)W3hh, 512, n0, k0, srow, skb, BsB, t);
      __syncthreads();
      mfma_phase4(AsB, BsB, acc, lane, wr, wc);
      __syncthreads();
    }
    epi_store_bf4(C3, 1024, m0, n0, lane, wr, wc, acc);
  }
}

// ---- K3: loss (blocks 0..511) + LSTM finish & scatter (blocks 512..1023) ----
__global__ __launch_bounds__(256) void k3_losslstm(
    const int* __restrict__ counts, int lvl, const int* __restrict__ lists,
    const ushort_t* __restrict__ C2, const ushort_t* __restrict__ C3,
    const ushort_t* __restrict__ Cpar, const ushort_t* __restrict__ EG,
    const float* __restrict__ b_topo, const float* __restrict__ b_pred,
    const float* __restrict__ b_ih, const float* __restrict__ b_hh,
    const int* __restrict__ features, const int* __restrict__ is_parent,
    const int* __restrict__ has_sib, const int* __restrict__ is_res,
    float* __restrict__ loss,
    ushort_t* __restrict__ h_state, ushort_t* __restrict__ c_state)
{
  const int count = min(counts[lvl], MAXM);
  if (blockIdx.x < 512){
    __shared__ float lsum[4];
    const int lane = threadIdx.x & 63;
    const int wvi = threadIdx.x >> 6;
    if (threadIdx.x < 4) lsum[threadIdx.x] = 0.0f;
    __syncthreads();
    for (int m = blockIdx.x*4 + wvi; m < count; m += 2048){
      const ushort_t* row = C2 + (size_t)m*640;
      int node = lists[lvl*MAXM + m];
      int feat = features[node];
      float mx = -1e30f, lf = 0.0f;
      float vals[16];
      #pragma unroll
      for (int i=0;i<2;i++){
        int s = lane + 64*i;
        if (s < 75){
          u16x8 raw = *(const u16x8*)((const char*)row + 16 + 16*s);
          float4v bp0 = *(const float4v*)(b_pred + 8*s);
          float4v bp1 = *(const float4v*)(b_pred + 8*s + 4);
          #pragma unroll
          for (int j=0;j<8;j++){
            float b = (j<4) ? bp0[j] : bp1[j-4];
            float v = bf2f(raw[j]) + b;
            vals[8*i+j] = v;
            mx = fmaxf(mx, v);
            if (8*s + j == feat) lf = v;
          }
        } else {
          #pragma unroll
          for (int j=0;j<8;j++) vals[8*i+j] = -1e30f;
        }
      }
      #pragma unroll
      for (int off=32;off>=1;off>>=1) mx = fmaxf(mx, __shfl_xor(mx, off));
      float s = 0.0f;
      #pragma unroll
      for (int i=0;i<16;i++) s += expf(vals[i]-mx);
      #pragma unroll
      for (int off=32;off>=1;off>>=1) s += __shfl_xor(s, off);
      #pragma unroll
      for (int off=32;off>=1;off>>=1) lf += __shfl_xor(lf, off);
      if (lane == 0){
        float ce = logf(s) + mx - lf;
        float bce = bcef(bf2f(row[0])+b_topo[0], (float)is_parent[node])
                  + bcef(bf2f(row[1])+b_topo[1], (float)has_sib[node])
                  + bcef(bf2f(row[2])+b_topo[2], (float)is_res[node]);
        atomicAdd(&lsum[wvi], ce + bce);
      }
    }
    __syncthreads();
    if (threadIdx.x == 0){
      atomicAdd(loss, (lsum[0]+lsum[1]+lsum[2]+lsum[3]) * INV_N);
    }
  } else {
    const int t = threadIdx.x;
    const float bi = b_ih[t]       + b_hh[t];
    const float bf = b_ih[256+t]   + b_hh[256+t];
    const float bg = b_ih[512+t]   + b_hh[512+t];
    const float bo = b_ih[768+t]   + b_hh[768+t];
    for (int m = (int)blockIdx.x - 512; m < count; m += 512){
      int node = lists[lvl*MAXM + m];
      int feat = features[node];
      u16x4 gv = *(const u16x4*)(C3 + (size_t)m*1024 + 4*t);     // PU@W_hh, interleaved
      u16x4 ev = *(const u16x4*)(EG + (size_t)feat*1024 + 4*t);  // emb@W_ih, interleaved
      float i_ = sigm(bf2f(gv[0]) + bf2f(ev[0]) + bi);
      float f_ = sigm(bf2f(gv[1]) + bf2f(ev[1]) + bf);
      float gg = tanhf(bf2f(gv[2]) + bf2f(ev[2]) + bg);
      float o_ = sigm(bf2f(gv[3]) + bf2f(ev[3]) + bo);
      float cn = f_*bf2f(Cpar[(size_t)m*LATENT+t]) + i_*gg;
      float hn = o_*tanhf(cn);
      h_state[(size_t)node*LATENT+t] = f2bf(hn);
      c_state[(size_t)node*LATENT+t] = f2bf(cn);
    }
  }
}

extern "C" void kernel_launch(void* const* d_in, const int* in_sizes, int n_in,
                              void* d_out, int out_size, void* d_ws, size_t ws_size,
                              hipStream_t stream)
{
  const float* z         = (const float*)d_in[0];
  const float* emb_table = (const float*)d_in[1];
  const float* W_l2h     = (const float*)d_in[2];
  const float* b_l2h     = (const float*)d_in[3];
  const float* W_ih      = (const float*)d_in[4];
  const float* W_hh      = (const float*)d_in[5];
  const float* b_ih      = (const float*)d_in[6];
  const float* b_hh      = (const float*)d_in[7];
  const float* W_ph1     = (const float*)d_in[8];
  const float* b_ph1     = (const float*)d_in[9];
  const float* W_ph2     = (const float*)d_in[10];
  const float* b_ph2     = (const float*)d_in[11];
  const float* W_gate    = (const float*)d_in[12];
  const float* b_gate    = (const float*)d_in[13];
  const float* W_topo    = (const float*)d_in[14];
  const float* b_topo    = (const float*)d_in[15];
  const float* W_pred    = (const float*)d_in[16];
  const float* b_pred    = (const float*)d_in[17];
  const int* features    = (const int*)d_in[18];
  const int* node_level  = (const int*)d_in[19];
  const int* parent_idx  = (const int*)d_in[20];
  const int* sibling_idx = (const int*)d_in[21];
  const int* has_prev    = (const int*)d_in[22];
  const int* tree_id     = (const int*)d_in[23];
  const int* is_parent   = (const int*)d_in[24];
  const int* has_sib     = (const int*)d_in[25];
  const int* is_res      = (const int*)d_in[26];

  char* ws = (char*)d_ws;
  size_t off = 0;
  auto alloc = [&](size_t bytes)->char*{
    char* p = ws + off; off += (bytes + 255) & ~(size_t)255; return p;
  };
  ushort_t* h_state = (ushort_t*)alloc((size_t)NNODES*LATENT*2);   // 33.5 MB
  ushort_t* c_state = (ushort_t*)alloc((size_t)NNODES*LATENT*2);   // 33.5 MB
  ushort_t* A2      = (ushort_t*)alloc((size_t)MAXM*LATENT*2);
  ushort_t* PU      = (ushort_t*)alloc((size_t)MAXM*LATENT*2);
  ushort_t* C1      = (ushort_t*)alloc((size_t)MAXM*512*2);
  ushort_t* C2      = (ushort_t*)alloc((size_t)MAXM*640*2);
  ushort_t* C3      = (ushort_t*)alloc((size_t)MAXM*1024*2);
  ushort_t* Cpar    = (ushort_t*)alloc((size_t)MAXM*LATENT*2);
  ushort_t* W1t     = (ushort_t*)alloc((size_t)512*512*2);
  ushort_t* W2t     = (ushort_t*)alloc((size_t)640*256*2);
  ushort_t* W3hh    = (ushort_t*)alloc((size_t)1024*256*2);
  ushort_t* W3ih    = (ushort_t*)alloc((size_t)1024*128*2);
  ushort_t* embbf   = (ushort_t*)alloc((size_t)640*128*2);
  ushort_t* EG      = (ushort_t*)alloc((size_t)640*1024*2);
  float*    root_h  = (float*)alloc((size_t)NTREES*LATENT*4);
  int*      lists   = (int*)alloc((size_t)NLEV*MAXM*4);
  int*      counts  = (int*)alloc(64);
  float*    zpage   = (float*)alloc(1024);
  float*    loss    = (float*)d_out;

  zero_kernel<<<1,256,0,stream>>>(loss, counts, zpage);
  prep_kernel<<<3520,256,0,stream>>>(W_ph1,W_ph2,W_gate,W_topo,W_pred,W_ih,W_hh,emb_table,
                                     W1t,W2t,W3hh,W3ih,embbf);
  eg_gemm<<<dim3(5,8),256,0,stream>>>(embbf, W3ih, EG);
  root_kernel<<<NTREES,LATENT,0,stream>>>(z, W_l2h, b_l2h, root_h);
  init_kernel<<<2048,LATENT,0,stream>>>(node_level, tree_id, root_h, h_state, c_state);
  build_lists_kernel<<<NNODES/256,256,0,stream>>>(node_level, counts, lists);

  for (int lvl=1; lvl<NLEV; lvl++){
    k1_gemm<<<dim3(MAXM/128,4),256,0,stream>>>(counts, lvl, lists,
        parent_idx, sibling_idx, has_prev, h_state, (const char*)zpage, W1t, C1);
    mid_kernel<<<512,256,0,stream>>>(counts, lvl, lists, parent_idx, sibling_idx,
        has_prev, h_state, c_state, C1, b_ph1, b_ph2, b_gate, A2, PU, Cpar);
    k2_fused<<<650,256,0,stream>>>(counts, lvl, A2, PU, W2t, W3hh, C2, C3);
    k3_losslstm<<<1024,256,0,stream>>>(counts, lvl, lists, C2, C3, Cpar, EG,
        b_topo, b_pred, b_ih, b_hh, features, is_parent, has_sib, is_res,
        loss, h_state, c_state);
  }
}